// Round 1
// baseline (908.639 us; speedup 1.0000x reference)
//
#include <hip/hip_runtime.h>
#include <hip/hip_bf16.h>
#include <math.h>

// Problem constants (from setup_inputs): B=8, H=W=128, C=hidden=256.
#define Bn   8
#define Hc   128
#define Wc   128
#define Cc   256
#define CHc  256
#define Nc   (Hc * Wc)          // 16384
#define CSZ  52                 // ceil(256/5): torch.chunk(.,5) chunk size
#define SPAD 2                  // SHIFT_SIZE//2

typedef unsigned short ushort8 __attribute__((ext_vector_type(8)));

__device__ __forceinline__ float bf2f(unsigned short u) {
    return __uint_as_float(((unsigned)u) << 16);
}
__device__ __forceinline__ unsigned short f2bf(float f) {
    unsigned u = __float_as_uint(f);
    unsigned r = (u + 0x7fffu + ((u >> 16) & 1u)) >> 16;   // RNE
    return (unsigned short)r;
}

// ---------------------------------------------------------------------------
// K1: h1[b,n,j] = b1[j] + sum_c x_shiftH[b,n,c] * w1[j,c]     (fp32 -> bf16)
// x_shiftH[b,(h,w),c] = x[b,(h - s_c, w),c], zero outside; s_c = c/52 - 2.
// 128x128 block tile, 256 threads, 8x8 micro-tile, K-tile 16.
// ---------------------------------------------------------------------------
__global__ __launch_bounds__(256)
void fc1_shift_kernel(const float* __restrict__ x, const float* __restrict__ w1,
                      const float* __restrict__ b1, unsigned short* __restrict__ h1)
{
    __shared__ float As[16][128];
    __shared__ float Bs[16][128];
    const int b  = blockIdx.z;
    const int m0 = blockIdx.x * 128;
    const int j0 = blockIdx.y * 128;
    const int tid = threadIdx.x;
    const int tx = tid & 15, ty = tid >> 4;
    const float* xb = x + (size_t)b * Nc * Cc;

    float acc[8][8] = {};
    for (int k0 = 0; k0 < Cc; k0 += 16) {
        const int kk = tid & 15;
        const int c  = k0 + kk;
        const int s  = c / CSZ - SPAD;
#pragma unroll
        for (int p = 0; p < 8; ++p) {
            const int r = (tid >> 4) + p * 16;      // 0..127
            const int n = m0 + r;
            const int hs = (n >> 7) - s;            // shifted h index
            float v = 0.f;
            if (hs >= 0 && hs < Hc) v = xb[(size_t)(n - s * Wc) * Cc + c];
            As[kk][r] = v;
        }
#pragma unroll
        for (int p = 0; p < 8; ++p) {
            const int r = (tid >> 4) + p * 16;
            Bs[kk][r] = w1[(size_t)(j0 + r) * Cc + c];
        }
        __syncthreads();
#pragma unroll
        for (int k = 0; k < 16; ++k) {
            const float4 a0 = *(const float4*)&As[k][ty * 8];
            const float4 a1 = *(const float4*)&As[k][ty * 8 + 4];
            const float4 b0 = *(const float4*)&Bs[k][tx * 8];
            const float4 b1v = *(const float4*)&Bs[k][tx * 8 + 4];
            const float av[8] = {a0.x, a0.y, a0.z, a0.w, a1.x, a1.y, a1.z, a1.w};
            const float bv[8] = {b0.x, b0.y, b0.z, b0.w, b1v.x, b1v.y, b1v.z, b1v.w};
#pragma unroll
            for (int i = 0; i < 8; ++i)
#pragma unroll
                for (int j = 0; j < 8; ++j) acc[i][j] += av[i] * bv[j];
        }
        __syncthreads();
    }

    float bias[8];
#pragma unroll
    for (int j = 0; j < 8; ++j) bias[j] = b1[j0 + tx * 8 + j];
#pragma unroll
    for (int i = 0; i < 8; ++i) {
        const int n = m0 + ty * 8 + i;
        ushort8 pk;
#pragma unroll
        for (int j = 0; j < 8; ++j) pk[j] = f2bf(acc[i][j] + bias[j]);
        *(ushort8*)(h1 + ((size_t)b * Nc + n) * CHc + j0 + tx * 8) = pk;
    }
}

// ---------------------------------------------------------------------------
// K2: depthwise 3x3 (cross-correlation, pad 1) + dw_b + exact GELU.
// bf16 in/out, fp32 accumulate. Each thread: 1 spatial pos x 8 channels.
// ---------------------------------------------------------------------------
__global__ __launch_bounds__(256)
void dwconv_gelu_kernel(const unsigned short* __restrict__ h1,
                        const float* __restrict__ dw_w, const float* __restrict__ dw_b,
                        unsigned short* __restrict__ g)
{
    __shared__ float wsm[9][CHc];   // wsm[tap][channel]
    for (int i = threadIdx.x; i < CHc * 9; i += 256)
        wsm[i % 9][i / 9] = dw_w[i];          // dw_w[(j)*9 + tap]
    __syncthreads();

    const int n_lin = blockIdx.x * 8 + (threadIdx.x >> 5);   // 0..B*N-1
    const int cg = (threadIdx.x & 31) * 8;                   // channel base
    const int b = n_lin >> 14;
    const int n = n_lin & (Nc - 1);
    const int hh = n >> 7, ww = n & 127;
    const size_t bN = (size_t)b * Nc;

    float acc[8];
#pragma unroll
    for (int c = 0; c < 8; ++c) acc[c] = dw_b[cg + c];

#pragma unroll
    for (int dy = -1; dy <= 1; ++dy) {
        const int y = hh + dy;
        if (y < 0 || y >= Hc) continue;
#pragma unroll
        for (int dx = -1; dx <= 1; ++dx) {
            const int xw = ww + dx;
            if (xw < 0 || xw >= Wc) continue;
            const int tap = (dy + 1) * 3 + (dx + 1);
            const ushort8 raw = *(const ushort8*)(h1 + (bN + y * Wc + xw) * CHc + cg);
#pragma unroll
            for (int c = 0; c < 8; ++c)
                acc[c] += bf2f(raw[c]) * wsm[tap][cg + c];
        }
    }

    ushort8 outv;
#pragma unroll
    for (int c = 0; c < 8; ++c) {
        const float v = acc[c];
        outv[c] = f2bf(0.5f * v * (1.0f + erff(v * 0.70710678118654752f)));
    }
    *(ushort8*)(g + (bN + n) * CHc + cg) = outv;
}

// ---------------------------------------------------------------------------
// K3: out[b,n,i] = b2[i] + sum_j g_shiftW[b,n,j] * w2[i,j]    (bf16 -> fp32)
// g_shiftW[b,(h,w),j] = g[b,(h, w - s_j),j], zero outside.
// ---------------------------------------------------------------------------
__global__ __launch_bounds__(256)
void fc2_shift_kernel(const unsigned short* __restrict__ g, const float* __restrict__ w2,
                      const float* __restrict__ b2, float* __restrict__ out)
{
    __shared__ float As[16][128];
    __shared__ float Bs[16][128];
    const int b  = blockIdx.z;
    const int m0 = blockIdx.x * 128;
    const int j0 = blockIdx.y * 128;
    const int tid = threadIdx.x;
    const int tx = tid & 15, ty = tid >> 4;
    const unsigned short* gb = g + (size_t)b * Nc * CHc;

    float acc[8][8] = {};
    for (int k0 = 0; k0 < CHc; k0 += 16) {
        const int kk = tid & 15;
        const int c  = k0 + kk;
        const int s  = c / CSZ - SPAD;
#pragma unroll
        for (int p = 0; p < 8; ++p) {
            const int r = (tid >> 4) + p * 16;
            const int n = m0 + r;
            const int wsft = (n & 127) - s;         // shifted w index
            float v = 0.f;
            if (wsft >= 0 && wsft < Wc) v = bf2f(gb[(size_t)(n - s) * CHc + c]);
            As[kk][r] = v;
        }
#pragma unroll
        for (int p = 0; p < 8; ++p) {
            const int r = (tid >> 4) + p * 16;
            Bs[kk][r] = w2[(size_t)(j0 + r) * CHc + c];
        }
        __syncthreads();
#pragma unroll
        for (int k = 0; k < 16; ++k) {
            const float4 a0 = *(const float4*)&As[k][ty * 8];
            const float4 a1 = *(const float4*)&As[k][ty * 8 + 4];
            const float4 b0 = *(const float4*)&Bs[k][tx * 8];
            const float4 b1v = *(const float4*)&Bs[k][tx * 8 + 4];
            const float av[8] = {a0.x, a0.y, a0.z, a0.w, a1.x, a1.y, a1.z, a1.w};
            const float bv[8] = {b0.x, b0.y, b0.z, b0.w, b1v.x, b1v.y, b1v.z, b1v.w};
#pragma unroll
            for (int i = 0; i < 8; ++i)
#pragma unroll
                for (int j = 0; j < 8; ++j) acc[i][j] += av[i] * bv[j];
        }
        __syncthreads();
    }

    float bias[8];
#pragma unroll
    for (int j = 0; j < 8; ++j) bias[j] = b2[j0 + tx * 8 + j];
#pragma unroll
    for (int i = 0; i < 8; ++i) {
        const int n = m0 + ty * 8 + i;
        float* op = out + ((size_t)b * Nc + n) * Cc + j0 + tx * 8;
        float4 o0, o1;
        o0.x = acc[i][0] + bias[0]; o0.y = acc[i][1] + bias[1];
        o0.z = acc[i][2] + bias[2]; o0.w = acc[i][3] + bias[3];
        o1.x = acc[i][4] + bias[4]; o1.y = acc[i][5] + bias[5];
        o1.z = acc[i][6] + bias[6]; o1.w = acc[i][7] + bias[7];
        *(float4*)op = o0;
        *(float4*)(op + 4) = o1;
    }
}

extern "C" void kernel_launch(void* const* d_in, const int* in_sizes, int n_in,
                              void* d_out, int out_size, void* d_ws, size_t ws_size,
                              hipStream_t stream) {
    // setup_inputs order: x, H, W, w1, b1, dw_w, dw_b, w2, b2
    const float* x    = (const float*)d_in[0];
    const float* w1   = (const float*)d_in[3];
    const float* b1   = (const float*)d_in[4];
    const float* dw_w = (const float*)d_in[5];
    const float* dw_b = (const float*)d_in[6];
    const float* w2   = (const float*)d_in[7];
    const float* b2   = (const float*)d_in[8];
    float* out = (float*)d_out;

    // ws layout: h1 (bf16, B*N*CH) | g (bf16, B*N*CH)  => 134 MB total
    unsigned short* h1 = (unsigned short*)d_ws;
    unsigned short* g  = h1 + (size_t)Bn * Nc * CHc;

    dim3 blk(256);
    fc1_shift_kernel<<<dim3(Nc / 128, CHc / 128, Bn), blk, 0, stream>>>(x, w1, b1, h1);
    dwconv_gelu_kernel<<<dim3(Bn * Nc / 8), blk, 0, stream>>>(h1, dw_w, dw_b, g);
    fc2_shift_kernel<<<dim3(Nc / 128, Cc / 128, Bn), blk, 0, stream>>>(g, w2, b2, out);
}

// Round 2
// 418.866 us; speedup vs baseline: 2.1693x; 2.1693x over previous
//
#include <hip/hip_runtime.h>
#include <hip/hip_bf16.h>
#include <math.h>

// B=8, H=W=128, C=hidden=256, N=16384, Mtot=131072.
#define Hc   128
#define Wc   128
#define Cc   256
#define Nc   (Hc * Wc)
#define Bn   8
#define Mtot (Bn * Nc)          // 131072
#define CSZ  52                 // ceil(256/5)
#define SPAD 2

typedef unsigned short ushort4v __attribute__((ext_vector_type(4)));
typedef unsigned short ushort8  __attribute__((ext_vector_type(8)));
typedef __bf16         bf16x8   __attribute__((ext_vector_type(8)));
typedef float          f32x4    __attribute__((ext_vector_type(4)));

__device__ __forceinline__ float bf2f(unsigned short u) {
    return __uint_as_float(((unsigned)u) << 16);
}
__device__ __forceinline__ unsigned short f2bf(float f) {   // RNE
    unsigned u = __float_as_uint(f);
    return (unsigned short)((u + 0x7fffu + ((u >> 16) & 1u)) >> 16);
}
// pack two floats -> two bf16 (round-half-up; bias negligible vs bf16 eps)
__device__ __forceinline__ unsigned pk2bf(float a, float b) {
    unsigned ua = __float_as_uint(a) + 0x8000u;
    unsigned ub = __float_as_uint(b) + 0x8000u;
    return __builtin_amdgcn_perm(ub, ua, 0x07060302);  // [ua.hi16 | ub.hi16<<16]
}
__device__ __forceinline__ void async16(const void* g, void* l) {
    __builtin_amdgcn_global_load_lds(
        (const __attribute__((address_space(1))) unsigned*)g,
        (__attribute__((address_space(3))) unsigned*)l, 16, 0, 0);
}

// ---------------------------------------------------------------------------
// P1: x (fp32, [B*N][256]) -> x_shifted (bf16), H-shift folded in.
// Thread: 4 channels (shift uniform: 52 % 4 == 0). 1 float4 load, 8B store.
// ---------------------------------------------------------------------------
__global__ __launch_bounds__(256)
void prep_xshift_kernel(const float* __restrict__ x, unsigned short* __restrict__ xs)
{
    const int gid = blockIdx.x * 256 + threadIdx.x;   // B*N*64 total
    const int grp = gid & 63;
    const int nl  = gid >> 6;                         // 0..131071
    const int c0  = grp * 4;
    const int s   = c0 / CSZ - SPAD;
    const int h   = (nl & (Nc - 1)) >> 7;
    const int hs  = h - s;
    float4 v = make_float4(0.f, 0.f, 0.f, 0.f);
    if (hs >= 0 && hs < Hc) v = *(const float4*)(x + ((size_t)nl - s * Wc) * Cc + c0);
    ushort4v o = { f2bf(v.x), f2bf(v.y), f2bf(v.z), f2bf(v.w) };
    *(ushort4v*)(xs + (size_t)nl * Cc + c0) = o;
}

// ---------------------------------------------------------------------------
// K1: h1 = x_shifted @ w1^T + b1  (bf16 A via global_load_lds, fp32 w1 packed
// to bf16 in-loop, 128x128 tile, BK=32, 16x16x32 MFMA, bf16 out via LDS repack)
// ---------------------------------------------------------------------------
__global__ __launch_bounds__(256)
void fc1_mfma_kernel(const unsigned short* __restrict__ A, const float* __restrict__ w1,
                     const float* __restrict__ b1, unsigned short* __restrict__ h1)
{
    __shared__ __bf16 As[128 * 32];                    // 8 KB, [m][k] row-major
    __shared__ __bf16 Bs[128 * 32];                    // 8 KB, [n][k] row-major
    __shared__ __align__(16) unsigned short Cs[128 * 136];  // 34 KB repack

    const int tid  = threadIdx.x;
    const int lane = tid & 63;
    const int wave = tid >> 6;
    const int wm = (wave >> 1) * 64, wn = (wave & 1) * 64;
    const size_t m0 = (size_t)blockIdx.x * 128;
    const int j0 = blockIdx.y * 128;

    const int idx0 = tid, idx1 = tid + 256;            // 16B chunks of A tile
    const int brow = tid >> 1, bch = (tid & 1) * 16;   // B staging mapping

    f32x4 acc[4][4] = {};
    for (int k0 = 0; k0 < Cc; k0 += 32) {
        // A: async global->LDS, 16B/lane, LDS = wave-uniform base + lane*16
        async16(A + (m0 + (idx0 >> 2)) * Cc + k0 + (idx0 & 3) * 8, As + idx0 * 8);
        async16(A + (m0 + (idx1 >> 2)) * Cc + k0 + (idx1 & 3) * 8, As + idx1 * 8);
        // B: fp32 load + pack to bf16 + LDS store (w1 is [out][k] = B^T layout)
        {
            const float* src = w1 + (size_t)(j0 + brow) * Cc + k0 + bch;
            float4 v0 = *(const float4*)(src);
            float4 v1 = *(const float4*)(src + 4);
            float4 v2 = *(const float4*)(src + 8);
            float4 v3 = *(const float4*)(src + 12);
            uint4 p0, p1;
            p0.x = pk2bf(v0.x, v0.y); p0.y = pk2bf(v0.z, v0.w);
            p0.z = pk2bf(v1.x, v1.y); p0.w = pk2bf(v1.z, v1.w);
            p1.x = pk2bf(v2.x, v2.y); p1.y = pk2bf(v2.z, v2.w);
            p1.z = pk2bf(v3.x, v3.y); p1.w = pk2bf(v3.z, v3.w);
            *(uint4*)(Bs + brow * 32 + bch)     = p0;
            *(uint4*)(Bs + brow * 32 + bch + 8) = p1;
        }
        __syncthreads();
        bf16x8 a[4], b[4];
        const int kq = (lane >> 4) * 8;
        const int r  = lane & 15;
#pragma unroll
        for (int i = 0; i < 4; ++i) {
            a[i] = *(const bf16x8*)(As + (wm + i * 16 + r) * 32 + kq);
            b[i] = *(const bf16x8*)(Bs + (wn + i * 16 + r) * 32 + kq);
        }
#pragma unroll
        for (int i = 0; i < 4; ++i)
#pragma unroll
            for (int j = 0; j < 4; ++j)
                acc[i][j] = __builtin_amdgcn_mfma_f32_16x16x32_bf16(a[i], b[j], acc[i][j], 0, 0, 0);
        __syncthreads();
    }

    // epilogue: + bias, bf16, LDS repack for coalesced stores
    const int cq = (lane >> 4) * 4;
    const int cc = lane & 15;
    float bv[4];
#pragma unroll
    for (int j = 0; j < 4; ++j) bv[j] = b1[j0 + wn + j * 16 + cc];
#pragma unroll
    for (int i = 0; i < 4; ++i)
#pragma unroll
        for (int j = 0; j < 4; ++j) {
            const int col = wn + j * 16 + cc;
#pragma unroll
            for (int rg = 0; rg < 4; ++rg)
                Cs[(wm + i * 16 + cq + rg) * 136 + col] = f2bf(acc[i][j][rg] + bv[j]);
        }
    __syncthreads();
    {
        const int row = tid >> 1, half = tid & 1;
        const unsigned short* src = Cs + row * 136 + half * 64;
        unsigned short* dst = h1 + (m0 + row) * Cc + j0 + half * 64;
#pragma unroll
        for (int i = 0; i < 8; ++i)
            *(uint4*)(dst + i * 8) = *(const uint4*)(src + i * 8);
    }
}

// ---------------------------------------------------------------------------
// border zeros for g_shifted: w in {0,1,126,127}, all channels (scatter
// overwrites the valid ones afterwards).
// ---------------------------------------------------------------------------
__global__ __launch_bounds__(256)
void zero_borders_kernel(unsigned short* __restrict__ gsh)
{
    const int gid = blockIdx.x * 256 + threadIdx.x;   // 131072 total
    const int cg  = gid & 31;
    const int rest = gid >> 5;                        // b*128*4 + h*4 + wi
    const int wi = rest & 3;
    const int bh = rest >> 2;                         // b*128 + h
    const int w  = (wi & 2) ? (wi + 124) : wi;        // 0,1,126,127
    uint4 z; z.x = z.y = z.z = z.w = 0u;
    *(uint4*)(gsh + ((size_t)bh * 128 + w) * Cc + cg * 8) = z;
}

// ---------------------------------------------------------------------------
// K2: depthwise 3x3 + bias + exact GELU, W-shift scattered into g_shifted.
// ---------------------------------------------------------------------------
__global__ __launch_bounds__(256)
void dwconv_gelu_scatter_kernel(const unsigned short* __restrict__ h1,
                                const float* __restrict__ dw_w, const float* __restrict__ dw_b,
                                unsigned short* __restrict__ gsh)
{
    __shared__ float wsm[9][256];   // swizzled: [tap][slot(c)], conflict-free reads
    for (int i = threadIdx.x; i < 9 * 256; i += 256) {
        const int tap = i % 9, c = i / 9;
        wsm[tap][(c >> 3) | ((c & 7) << 5)] = dw_w[i];
    }
    __syncthreads();

    const int n_lin = blockIdx.x * 8 + (threadIdx.x >> 5);
    const int li = threadIdx.x & 31;
    const int cg = li * 8;
    const int b = n_lin >> 14;
    const int n = n_lin & (Nc - 1);
    const int hh = n >> 7, ww = n & 127;
    const size_t bN = (size_t)b * Nc;

    float acc[8];
#pragma unroll
    for (int c = 0; c < 8; ++c) acc[c] = dw_b[cg + c];

#pragma unroll
    for (int dy = -1; dy <= 1; ++dy) {
        const int y = hh + dy;
        if (y < 0 || y >= Hc) continue;
#pragma unroll
        for (int dx = -1; dx <= 1; ++dx) {
            const int xw = ww + dx;
            if (xw < 0 || xw >= Wc) continue;
            const int tap = (dy + 1) * 3 + (dx + 1);
            const ushort8 raw = *(const ushort8*)(h1 + (bN + y * Wc + xw) * Cc + cg);
#pragma unroll
            for (int c = 0; c < 8; ++c)
                acc[c] += bf2f(raw[c]) * wsm[tap][li | (c << 5)];
        }
    }

    unsigned short ov[8];
#pragma unroll
    for (int c = 0; c < 8; ++c) {
        const float v = acc[c];
        ov[c] = f2bf(0.5f * v * (1.0f + erff(v * 0.70710678118654752f)));
    }
    // W-shift scatter, uniform per 4-channel half
    const int s0 = cg / CSZ - SPAD;
    const int s1 = (cg + 4) / CSZ - SPAD;
    const int w0 = ww + s0, w1 = ww + s1;
    if ((unsigned)w0 < (unsigned)Wc) {
        ushort4v t = { ov[0], ov[1], ov[2], ov[3] };
        *(ushort4v*)(gsh + (bN + hh * Wc + w0) * Cc + cg) = t;
    }
    if ((unsigned)w1 < (unsigned)Wc) {
        ushort4v t = { ov[4], ov[5], ov[6], ov[7] };
        *(ushort4v*)(gsh + (bN + hh * Wc + w1) * Cc + cg + 4) = t;
    }
}

// ---------------------------------------------------------------------------
// K3: out = g_shifted @ w2^T + b2  (same GEMM, fp32 direct store)
// ---------------------------------------------------------------------------
__global__ __launch_bounds__(256)
void fc2_mfma_kernel(const unsigned short* __restrict__ A, const float* __restrict__ w2,
                     const float* __restrict__ b2, float* __restrict__ out)
{
    __shared__ __bf16 As[128 * 32];
    __shared__ __bf16 Bs[128 * 32];

    const int tid  = threadIdx.x;
    const int lane = tid & 63;
    const int wave = tid >> 6;
    const int wm = (wave >> 1) * 64, wn = (wave & 1) * 64;
    const size_t m0 = (size_t)blockIdx.x * 128;
    const int j0 = blockIdx.y * 128;

    const int idx0 = tid, idx1 = tid + 256;
    const int brow = tid >> 1, bch = (tid & 1) * 16;

    f32x4 acc[4][4] = {};
    for (int k0 = 0; k0 < Cc; k0 += 32) {
        async16(A + (m0 + (idx0 >> 2)) * Cc + k0 + (idx0 & 3) * 8, As + idx0 * 8);
        async16(A + (m0 + (idx1 >> 2)) * Cc + k0 + (idx1 & 3) * 8, As + idx1 * 8);
        {
            const float* src = w2 + (size_t)(j0 + brow) * Cc + k0 + bch;
            float4 v0 = *(const float4*)(src);
            float4 v1 = *(const float4*)(src + 4);
            float4 v2 = *(const float4*)(src + 8);
            float4 v3 = *(const float4*)(src + 12);
            uint4 p0, p1;
            p0.x = pk2bf(v0.x, v0.y); p0.y = pk2bf(v0.z, v0.w);
            p0.z = pk2bf(v1.x, v1.y); p0.w = pk2bf(v1.z, v1.w);
            p1.x = pk2bf(v2.x, v2.y); p1.y = pk2bf(v2.z, v2.w);
            p1.z = pk2bf(v3.x, v3.y); p1.w = pk2bf(v3.z, v3.w);
            *(uint4*)(Bs + brow * 32 + bch)     = p0;
            *(uint4*)(Bs + brow * 32 + bch + 8) = p1;
        }
        __syncthreads();
        bf16x8 a[4], b[4];
        const int kq = (lane >> 4) * 8;
        const int r  = lane & 15;
#pragma unroll
        for (int i = 0; i < 4; ++i) {
            a[i] = *(const bf16x8*)(As + (wm + i * 16 + r) * 32 + kq);
            b[i] = *(const bf16x8*)(Bs + (wn + i * 16 + r) * 32 + kq);
        }
#pragma unroll
        for (int i = 0; i < 4; ++i)
#pragma unroll
            for (int j = 0; j < 4; ++j)
                acc[i][j] = __builtin_amdgcn_mfma_f32_16x16x32_bf16(a[i], b[j], acc[i][j], 0, 0, 0);
        __syncthreads();
    }

    const int cq = (lane >> 4) * 4;
    const int cc = lane & 15;
    float bv[4];
#pragma unroll
    for (int j = 0; j < 4; ++j) bv[j] = b2[j0 + wn + j * 16 + cc];
#pragma unroll
    for (int i = 0; i < 4; ++i)
#pragma unroll
        for (int j = 0; j < 4; ++j) {
            const int col = j0 + wn + j * 16 + cc;
#pragma unroll
            for (int rg = 0; rg < 4; ++rg)
                out[(m0 + wm + i * 16 + cq + rg) * Cc + col] = acc[i][j][rg] + bv[j];
        }
}

extern "C" void kernel_launch(void* const* d_in, const int* in_sizes, int n_in,
                              void* d_out, int out_size, void* d_ws, size_t ws_size,
                              hipStream_t stream) {
    // inputs: x, H, W, w1, b1, dw_w, dw_b, w2, b2
    const float* x    = (const float*)d_in[0];
    const float* w1   = (const float*)d_in[3];
    const float* b1   = (const float*)d_in[4];
    const float* dw_w = (const float*)d_in[5];
    const float* dw_b = (const float*)d_in[6];
    const float* w2   = (const float*)d_in[7];
    const float* b2   = (const float*)d_in[8];
    float* out = (float*)d_out;

    // ws: [0,64MB) = x_shifted, later reused as g_shifted; [64MB,128MB) = h1
    unsigned short* xs  = (unsigned short*)d_ws;
    unsigned short* h1  = xs + (size_t)Mtot * Cc;
    unsigned short* gsh = xs;   // alias: xs dead after fc1

    prep_xshift_kernel<<<dim3(Mtot * 64 / 256), dim3(256), 0, stream>>>(x, xs);
    fc1_mfma_kernel<<<dim3(Mtot / 128, 2), dim3(256), 0, stream>>>(xs, w1, b1, h1);
    zero_borders_kernel<<<dim3(512), dim3(256), 0, stream>>>(gsh);
    dwconv_gelu_scatter_kernel<<<dim3(Mtot / 8), dim3(256), 0, stream>>>(h1, dw_w, dw_b, gsh);
    fc2_mfma_kernel<<<dim3(Mtot / 128, 2), dim3(256), 0, stream>>>(gsh, w2, b2, out);
}

// Round 4
// 388.470 us; speedup vs baseline: 2.3390x; 1.0782x over previous
//
#include <hip/hip_runtime.h>
#include <hip/hip_bf16.h>
#include <math.h>

// B=8, H=W=128, C=hidden=256, N=16384, Mtot=131072.
#define Hc   128
#define Wc   128
#define Cc   256
#define Nc   (Hc * Wc)
#define Bn   8
#define Mtot (Bn * Nc)          // 131072
#define CSZ  52                 // ceil(256/5)
#define SPAD 2

typedef unsigned short ushort4v __attribute__((ext_vector_type(4)));
typedef unsigned short ushort8  __attribute__((ext_vector_type(8)));
typedef __bf16         bf16x8   __attribute__((ext_vector_type(8)));
typedef float          f32x4    __attribute__((ext_vector_type(4)));

__device__ __forceinline__ float bf2f(unsigned short u) {
    return __uint_as_float(((unsigned)u) << 16);
}
__device__ __forceinline__ unsigned short f2bf(float f) {   // RNE
    unsigned u = __float_as_uint(f);
    return (unsigned short)((u + 0x7fffu + ((u >> 16) & 1u)) >> 16);
}
// pack two floats -> two bf16 (a -> low16). Round-half-up (ok vs bf16 eps).
__device__ __forceinline__ unsigned pk2bf(float a, float b) {
    unsigned ua = __float_as_uint(a) + 0x8000u;
    unsigned ub = __float_as_uint(b) + 0x8000u;
    return __builtin_amdgcn_perm(ub, ua, 0x07060302);
}
__device__ __forceinline__ void async16(const void* g, void* l) {
    __builtin_amdgcn_global_load_lds(
        (const __attribute__((address_space(1))) unsigned*)g,
        (__attribute__((address_space(3))) unsigned*)l, 16, 0, 0);
}

// ---------------------------------------------------------------------------
// P0: w1 fp32 -> bf16 (into d_out head, dead until fc2 rewrites all of out);
//     dw_w [ch][tap] -> dwT [tap][ch] fp32.
// ---------------------------------------------------------------------------
__global__ __launch_bounds__(256)
void wprep_kernel(const float* __restrict__ w1, const float* __restrict__ dw_w,
                  unsigned short* __restrict__ w1b, float* __restrict__ dwT)
{
    const int g = blockIdx.x * 256 + threadIdx.x;   // 16384 threads
    {
        float4 a = *(const float4*)(w1 + (size_t)g * 4);
        ushort4v o = { f2bf(a.x), f2bf(a.y), f2bf(a.z), f2bf(a.w) };
        *(ushort4v*)(w1b + (size_t)g * 4) = o;
    }
    if (g < 9 * Cc) dwT[(g % 9) * Cc + g / 9] = dw_w[g];
}

// ---------------------------------------------------------------------------
// K1: h1 = shiftH(x) @ w1^T + b1. H-shift fused into fp32 A staging (pack to
// bf16 in-reg); B tile async bf16. 128x128 tile, BK=32, 16x16x32 MFMA.
// Block row-tile = one (b,h) image row, so h is block-uniform.
// ---------------------------------------------------------------------------
__global__ __launch_bounds__(256)
void fc1_mfma_kernel(const float* __restrict__ x, const unsigned short* __restrict__ w1b,
                     const float* __restrict__ b1, unsigned short* __restrict__ h1)
{
    __shared__ __bf16 As[128 * 32];
    __shared__ __bf16 Bs[128 * 32];
    __shared__ __align__(16) unsigned short Cs[128 * 136];

    const int tid  = threadIdx.x;
    const int lane = tid & 63;
    const int wave = tid >> 6;
    const int wm = (wave >> 1) * 64, wn = (wave & 1) * 64;
    const int bx = blockIdx.x;                 // b*128 + h
    const size_t m0 = (size_t)bx * 128;
    const int j0 = blockIdx.y * 128;
    const int bb = bx >> 7, hh = bx & 127;
    const int r = tid >> 1, half = tid & 1;    // A staging: row r, k-half
    const int idx0 = tid, idx1 = tid + 256;    // B staging 16B chunks

    f32x4 acc[4][4] = {};
    for (int k0 = 0; k0 < Cc; k0 += 32) {
        // B: async bf16 global->LDS
        async16(w1b + (size_t)(j0 + (idx0 >> 2)) * Cc + k0 + (idx0 & 3) * 8, Bs + idx0 * 8);
        async16(w1b + (size_t)(j0 + (idx1 >> 2)) * Cc + k0 + (idx1 & 3) * 8, Bs + idx1 * 8);
        // A: fp32 load with H-shift + pack to bf16
        {
            const int kb = k0 + half * 16;
            unsigned p[8];
#pragma unroll
            for (int j = 0; j < 4; ++j) {
                const int c  = kb + j * 4;
                const int s  = c / CSZ - SPAD;
                const int hs = hh - s;
                float4 v = make_float4(0.f, 0.f, 0.f, 0.f);
                if (hs >= 0 && hs < Hc)
                    v = *(const float4*)(x + ((size_t)(bb * Nc + hs * Wc + r)) * Cc + c);
                p[j * 2]     = pk2bf(v.x, v.y);
                p[j * 2 + 1] = pk2bf(v.z, v.w);
            }
            uint4 q0, q1;
            q0.x = p[0]; q0.y = p[1]; q0.z = p[2]; q0.w = p[3];
            q1.x = p[4]; q1.y = p[5]; q1.z = p[6]; q1.w = p[7];
            *(uint4*)(As + r * 32 + half * 16)     = q0;
            *(uint4*)(As + r * 32 + half * 16 + 8) = q1;
        }
        __syncthreads();
        bf16x8 a[4], b[4];
        const int kq = (lane >> 4) * 8;
        const int rr = lane & 15;
#pragma unroll
        for (int i = 0; i < 4; ++i) {
            a[i] = *(const bf16x8*)(As + (wm + i * 16 + rr) * 32 + kq);
            b[i] = *(const bf16x8*)(Bs + (wn + i * 16 + rr) * 32 + kq);
        }
#pragma unroll
        for (int i = 0; i < 4; ++i)
#pragma unroll
            for (int j = 0; j < 4; ++j)
                acc[i][j] = __builtin_amdgcn_mfma_f32_16x16x32_bf16(a[i], b[j], acc[i][j], 0, 0, 0);
        __syncthreads();
    }

    const int cq = (lane >> 4) * 4;
    const int cc = lane & 15;
    float bv[4];
#pragma unroll
    for (int j = 0; j < 4; ++j) bv[j] = b1[j0 + wn + j * 16 + cc];
#pragma unroll
    for (int i = 0; i < 4; ++i)
#pragma unroll
        for (int j = 0; j < 4; ++j) {
            const int col = wn + j * 16 + cc;
#pragma unroll
            for (int rg = 0; rg < 4; ++rg)
                Cs[(wm + i * 16 + cq + rg) * 136 + col] = f2bf(acc[i][j][rg] + bv[j]);
        }
    __syncthreads();
    {
        const int row = tid >> 1, hf = tid & 1;
        const unsigned short* src = Cs + row * 136 + hf * 64;
        unsigned short* dst = h1 + (m0 + row) * Cc + j0 + hf * 64;
#pragma unroll
        for (int i = 0; i < 8; ++i)
            *(uint4*)(dst + i * 8) = *(const uint4*)(src + i * 8);
    }
}

// ---------------------------------------------------------------------------
// border zeros for g_shifted: w in {0,1,126,127}, all channels.
// ---------------------------------------------------------------------------
__global__ __launch_bounds__(256)
void zero_borders_kernel(unsigned short* __restrict__ gsh)
{
    const int gid = blockIdx.x * 256 + threadIdx.x;   // 131072 total
    const int cg  = gid & 31;
    const int rest = gid >> 5;
    const int wi = rest & 3;
    const int bh = rest >> 2;                         // b*128 + h
    const int w  = (wi & 2) ? (wi + 124) : wi;        // 0,1,126,127
    uint4 z; z.x = z.y = z.z = z.w = 0u;
    *(uint4*)(gsh + ((size_t)bh * 128 + w) * Cc + cg * 8) = z;
}

// ---------------------------------------------------------------------------
// K2: depthwise 3x3 + bias + GELU(sigmoid-form) + W-shift scatter.
// 256 threads = 32 channel-groups (t&31) x 8 w-quads (t>>5).
// Block = quarter of one (b,h) row; grid.x = 4 * 1024.
// ---------------------------------------------------------------------------
__global__ __launch_bounds__(256)
void dwconv_gelu_scatter_kernel(const unsigned short* __restrict__ h1,
                                const float* __restrict__ dwT, const float* __restrict__ dw_b,
                                unsigned short* __restrict__ gsh)
{
    const int t   = threadIdx.x;
    const int cg  = t & 31;           // channel group (8 ch): covers 256 ch
    const int wq  = t >> 5;           // w-quad 0..7
    const int c0  = cg * 8;
    const int bh  = blockIdx.x >> 2;  // b*128 + h
    const int qtr = blockIdx.x & 3;   // quarter-row
    const int bb  = bh >> 7, hh = bh & 127;
    const size_t rowb = (size_t)bb * Nc + (size_t)hh * Wc;
    const int wbase = qtr * 32 + wq * 4 - 1;

    float acc[4][8];
    {
        float4 a0 = *(const float4*)(dw_b + c0);
        float4 a1 = *(const float4*)(dw_b + c0 + 4);
#pragma unroll
        for (int i = 0; i < 4; ++i) {
            acc[i][0] = a0.x; acc[i][1] = a0.y; acc[i][2] = a0.z; acc[i][3] = a0.w;
            acc[i][4] = a1.x; acc[i][5] = a1.y; acc[i][6] = a1.z; acc[i][7] = a1.w;
        }
    }

#pragma unroll
    for (int dy = -1; dy <= 1; ++dy) {
        const int y = hh + dy;
        if (y < 0 || y >= Hc) continue;          // block-uniform
        const unsigned short* rp = h1 + ((size_t)bb * Nc + (size_t)y * Wc) * Cc + c0;
        float in[6][8];
#pragma unroll
        for (int dx = 0; dx < 6; ++dx) {
            const int w = wbase + dx;
            ushort8 raw = {0, 0, 0, 0, 0, 0, 0, 0};
            if (w >= 0 && w < Wc) raw = *(const ushort8*)(rp + (size_t)w * Cc);
#pragma unroll
            for (int c = 0; c < 8; ++c) in[dx][c] = bf2f(raw[c]);
        }
        const float* wrow = dwT + (dy + 1) * 3 * Cc + c0;
        float wr[3][8];
#pragma unroll
        for (int tx = 0; tx < 3; ++tx) {
            float4 wa = *(const float4*)(wrow + tx * Cc);
            float4 wb = *(const float4*)(wrow + tx * Cc + 4);
            wr[tx][0] = wa.x; wr[tx][1] = wa.y; wr[tx][2] = wa.z; wr[tx][3] = wa.w;
            wr[tx][4] = wb.x; wr[tx][5] = wb.y; wr[tx][6] = wb.z; wr[tx][7] = wb.w;
        }
#pragma unroll
        for (int i = 0; i < 4; ++i)
#pragma unroll
            for (int tx = 0; tx < 3; ++tx)
#pragma unroll
                for (int c = 0; c < 8; ++c)
                    acc[i][c] += in[i + tx][c] * wr[tx][c];
    }

    const int s0 = c0 / CSZ - SPAD;
    const int s1 = (c0 + 4) / CSZ - SPAD;
#pragma unroll
    for (int i = 0; i < 4; ++i) {
        float g[8];
#pragma unroll
        for (int c = 0; c < 8; ++c) {
            const float v = acc[i][c];
            // gelu(v) ~= v * sigmoid(1.59576912*v + 0.07135482*v^3)
            const float u = v * v;
            const float a = __builtin_fmaf(0.0713548162f, u, 1.5957691216f);
            const float e = __expf(v * a);
            g[c] = v * e * __builtin_amdgcn_rcpf(e + 1.0f);
        }
        uint2 lo, hi;
        lo.x = pk2bf(g[0], g[1]); lo.y = pk2bf(g[2], g[3]);
        hi.x = pk2bf(g[4], g[5]); hi.y = pk2bf(g[6], g[7]);
        const int wo = wbase + 1 + i;
        const int w0 = wo + s0, w1 = wo + s1;
        if ((unsigned)w0 < (unsigned)Wc) *(uint2*)(gsh + (rowb + w0) * Cc + c0)     = lo;
        if ((unsigned)w1 < (unsigned)Wc) *(uint2*)(gsh + (rowb + w1) * Cc + c0 + 4) = hi;
    }
}

// ---------------------------------------------------------------------------
// K3: out = g_shifted @ w2^T + b2 (bf16 A async, fp32 w2 packed in-loop).
// ---------------------------------------------------------------------------
__global__ __launch_bounds__(256)
void fc2_mfma_kernel(const unsigned short* __restrict__ A, const float* __restrict__ w2,
                     const float* __restrict__ b2, float* __restrict__ out)
{
    __shared__ __bf16 As[128 * 32];
    __shared__ __bf16 Bs[128 * 32];

    const int tid  = threadIdx.x;
    const int lane = tid & 63;
    const int wave = tid >> 6;
    const int wm = (wave >> 1) * 64, wn = (wave & 1) * 64;
    const size_t m0 = (size_t)blockIdx.x * 128;
    const int j0 = blockIdx.y * 128;

    const int idx0 = tid, idx1 = tid + 256;
    const int brow = tid >> 1, bch = (tid & 1) * 16;

    f32x4 acc[4][4] = {};
    for (int k0 = 0; k0 < Cc; k0 += 32) {
        async16(A + (m0 + (idx0 >> 2)) * Cc + k0 + (idx0 & 3) * 8, As + idx0 * 8);
        async16(A + (m0 + (idx1 >> 2)) * Cc + k0 + (idx1 & 3) * 8, As + idx1 * 8);
        {
            const float* src = w2 + (size_t)(j0 + brow) * Cc + k0 + bch;
            float4 v0 = *(const float4*)(src);
            float4 v1 = *(const float4*)(src + 4);
            float4 v2 = *(const float4*)(src + 8);
            float4 v3 = *(const float4*)(src + 12);
            uint4 p0, p1;
            p0.x = pk2bf(v0.x, v0.y); p0.y = pk2bf(v0.z, v0.w);
            p0.z = pk2bf(v1.x, v1.y); p0.w = pk2bf(v1.z, v1.w);
            p1.x = pk2bf(v2.x, v2.y); p1.y = pk2bf(v2.z, v2.w);
            p1.z = pk2bf(v3.x, v3.y); p1.w = pk2bf(v3.z, v3.w);
            *(uint4*)(Bs + brow * 32 + bch)     = p0;
            *(uint4*)(Bs + brow * 32 + bch + 8) = p1;
        }
        __syncthreads();
        bf16x8 a[4], b[4];
        const int kq = (lane >> 4) * 8;
        const int rr = lane & 15;
#pragma unroll
        for (int i = 0; i < 4; ++i) {
            a[i] = *(const bf16x8*)(As + (wm + i * 16 + rr) * 32 + kq);
            b[i] = *(const bf16x8*)(Bs + (wn + i * 16 + rr) * 32 + kq);
        }
#pragma unroll
        for (int i = 0; i < 4; ++i)
#pragma unroll
            for (int j = 0; j < 4; ++j)
                acc[i][j] = __builtin_amdgcn_mfma_f32_16x16x32_bf16(a[i], b[j], acc[i][j], 0, 0, 0);
        __syncthreads();
    }

    const int cq = (lane >> 4) * 4;
    const int cc = lane & 15;
    float bv[4];
#pragma unroll
    for (int j = 0; j < 4; ++j) bv[j] = b2[j0 + wn + j * 16 + cc];
#pragma unroll
    for (int i = 0; i < 4; ++i)
#pragma unroll
        for (int j = 0; j < 4; ++j) {
            const int col = j0 + wn + j * 16 + cc;
#pragma unroll
            for (int rg = 0; rg < 4; ++rg)
                out[(m0 + wm + i * 16 + cq + rg) * Cc + col] = acc[i][j][rg] + bv[j];
        }
}

extern "C" void kernel_launch(void* const* d_in, const int* in_sizes, int n_in,
                              void* d_out, int out_size, void* d_ws, size_t ws_size,
                              hipStream_t stream) {
    // inputs: x, H, W, w1, b1, dw_w, dw_b, w2, b2
    const float* x    = (const float*)d_in[0];
    const float* w1   = (const float*)d_in[3];
    const float* b1   = (const float*)d_in[4];
    const float* dw_w = (const float*)d_in[5];
    const float* dw_b = (const float*)d_in[6];
    const float* w2   = (const float*)d_in[7];
    const float* b2   = (const float*)d_in[8];
    float* out = (float*)d_out;

    // ws: [0,64MB) h1 bf16; [64MB,128MB) g_shifted bf16
    unsigned short* h1  = (unsigned short*)d_ws;
    unsigned short* gsh = h1 + (size_t)Mtot * Cc;
    // w1(bf16) + dwT(fp32) live in d_out's head: dead until fc2 fully
    // rewrites every element of out (fc1 reads w1b before any out write;
    // conv reads dwT before fc2 launches).
    unsigned short* w1b = (unsigned short*)d_out;          // 128 KB
    float*          dwT = (float*)(w1b + 65536);           // 9 KB

    wprep_kernel<<<dim3(64), dim3(256), 0, stream>>>(w1, dw_w, w1b, dwT);
    fc1_mfma_kernel<<<dim3(Mtot / 128, 2), dim3(256), 0, stream>>>(x, w1b, b1, h1);
    zero_borders_kernel<<<dim3(512), dim3(256), 0, stream>>>(gsh);
    dwconv_gelu_scatter_kernel<<<dim3(4 * Mtot / 128), dim3(256), 0, stream>>>(h1, dwT, dw_b, gsh);
    fc2_mfma_kernel<<<dim3(Mtot / 128, 2), dim3(256), 0, stream>>>(gsh, w2, b2, out);
}